// Round 1
// baseline (120328.564 us; speedup 1.0000x reference)
//
#include <hip/hip_runtime.h>
#include <hip/hip_fp16.h>
#include <hip/hip_bf16.h>

#define DM   256      // d_model
#define DI   512      // d_inner
#define TG   768      // 3*d_model
#define TSEQ 4096
#define NB   8
#define MTOT (NB*TSEQ) // 32768

typedef _Float16 h2f __attribute__((ext_vector_type(2)));

// ---------------- Phase 1: tiled fp32 GEMM, C = act(A @ W^T + bias) in fp16 ----
// A: [M,K] (fp32 or fp16), W: [N,K] fp32 row-major, C: [M,N] fp16
// 256 threads, 128x128 tile, BK=16, 8x8 micro-tile.
template<bool A_HALF, bool GELU_ACT>
__global__ __launch_bounds__(256) void gemm_bias(
    const void* __restrict__ Ap, const float* __restrict__ W,
    const float* __restrict__ bias, __half* __restrict__ C,
    int M, int N, int K)
{
  __shared__ float As[16][132];   // transposed: [k][m]
  __shared__ float Ws[16][132];   // transposed: [k][n]
  const int tid = threadIdx.x;
  const int tx = tid & 15, ty = tid >> 4;
  const int m0 = blockIdx.y * 128;
  const int n0 = blockIdx.x * 128;

  float acc[8][8] = {};

  for (int k0 = 0; k0 < K; k0 += 16) {
    // ---- stage A tile ----
    if constexpr (A_HALF) {
      const __half* A = (const __half*)Ap;
      int r = tid >> 1, seg = (tid & 1) * 8;          // 8 halves per thread
      float4 raw = *(const float4*)(A + (size_t)(m0 + r) * K + k0 + seg);
      const __half* hv = (const __half*)&raw;
      #pragma unroll
      for (int q = 0; q < 8; q++) As[seg + q][r] = __half2float(hv[q]);
    } else {
      const float* A = (const float*)Ap;
      #pragma unroll
      for (int rep = 0; rep < 2; rep++) {
        int r = (tid >> 2) + rep * 64;
        int seg = (tid & 3) * 4;
        float4 v = *(const float4*)(A + (size_t)(m0 + r) * K + k0 + seg);
        As[seg + 0][r] = v.x; As[seg + 1][r] = v.y;
        As[seg + 2][r] = v.z; As[seg + 3][r] = v.w;
      }
    }
    // ---- stage W tile ----
    #pragma unroll
    for (int rep = 0; rep < 2; rep++) {
      int r = (tid >> 2) + rep * 64;
      int seg = (tid & 3) * 4;
      float4 v = *(const float4*)(W + (size_t)(n0 + r) * K + k0 + seg);
      Ws[seg + 0][r] = v.x; Ws[seg + 1][r] = v.y;
      Ws[seg + 2][r] = v.z; Ws[seg + 3][r] = v.w;
    }
    __syncthreads();
    #pragma unroll
    for (int kk = 0; kk < 16; ++kk) {
      float a[8], b[8];
      *(float4*)&a[0] = *(const float4*)&As[kk][ty * 8];
      *(float4*)&a[4] = *(const float4*)&As[kk][ty * 8 + 4];
      *(float4*)&b[0] = *(const float4*)&Ws[kk][tx * 8];
      *(float4*)&b[4] = *(const float4*)&Ws[kk][tx * 8 + 4];
      #pragma unroll
      for (int i = 0; i < 8; i++)
        #pragma unroll
        for (int j = 0; j < 8; j++)
          acc[i][j] += a[i] * b[j];
    }
    __syncthreads();
  }

  #pragma unroll
  for (int i = 0; i < 8; i++) {
    int m = m0 + ty * 8 + i;
    #pragma unroll
    for (int j = 0; j < 8; j++) {
      int n = n0 + tx * 8 + j;
      float v = acc[i][j] + bias[n];
      if constexpr (GELU_ACT) {
        v = 0.5f * v * (1.0f + erff(v * 0.70710678118654752f));  // exact GELU
      }
      C[(size_t)m * N + n] = __float2half(v);
    }
  }
}

// ---------------- Phase 2: persistent GRU scan, one block per batch ----------
// 768 threads; thread j owns gate-row j of W_hh resident in VGPRs (128 x f16x2).
// h state broadcast via LDS (same-address ds reads = broadcast, conflict-free).
__global__ __launch_bounds__(768) void gru_scan(
    const __half* __restrict__ gx,   // [B, T, 768] fp16 (includes b_ih)
    const float*  __restrict__ Whh,  // [768, 256]
    const float*  __restrict__ bhh,  // [768]
    float* __restrict__ out)         // [B, T, 256]
{
  const int b = blockIdx.x;
  const int j = threadIdx.x;   // 0..767

  __shared__ __align__(16) _Float16 h16[DM];  // f16 copy of state for dot input
  __shared__ float gsig[2 * DM];              // r, z sigmoids

  // Load W_hh row j -> 128 packed f16x2 registers
  h2f w[128];
  const float* wrow = Whh + (size_t)j * DM;
  #pragma unroll 4
  for (int k4 = 0; k4 < 64; k4++) {
    float4 f = ((const float4*)wrow)[k4];
    h2f t0; t0[0] = (_Float16)f.x; t0[1] = (_Float16)f.y;
    h2f t1; t1[0] = (_Float16)f.z; t1[1] = (_Float16)f.w;
    w[2 * k4]     = t0;
    w[2 * k4 + 1] = t1;
  }
  const float bias = bhh[j];
  float hloc = 0.0f;           // fp32 state (only meaningful for n-threads)

  if (j < DM) h16[j] = (_Float16)0.0f;
  __syncthreads();

  const __half* gxb = gx + (size_t)b * TSEQ * TG;
  float* outb = out + (size_t)b * TSEQ * DM;

  float gxv = __half2float(gxb[j]);

  for (int t = 0; t < TSEQ; ++t) {
    // ---- gh_j = b_hh[j] + dot(W_hh[j,:], h_prev) via v_dot2_f32_f16 ----
    float a0 = bias, a1 = 0.f, a2 = 0.f, a3 = 0.f;
    const h2f* hp = (const h2f*)h16;
    #pragma unroll
    for (int k = 0; k < 32; k++) {
      a0 = __builtin_amdgcn_fdot2(w[4 * k + 0], hp[4 * k + 0], a0, false);
      a1 = __builtin_amdgcn_fdot2(w[4 * k + 1], hp[4 * k + 1], a1, false);
      a2 = __builtin_amdgcn_fdot2(w[4 * k + 2], hp[4 * k + 2], a2, false);
      a3 = __builtin_amdgcn_fdot2(w[4 * k + 3], hp[4 * k + 3], a3, false);
    }
    float gh = (a0 + a1) + (a2 + a3);

    // prefetch next timestep's gx
    float gxn = 0.f;
    if (t + 1 < TSEQ) gxn = __half2float(gxb[(size_t)(t + 1) * TG + j]);

    if (j < 2 * DM) {
      // r (j<256) and z (256<=j<512) gates
      float s = 1.0f / (1.0f + __expf(-(gxv + gh)));
      gsig[j] = s;
    }
    __syncthreads();
    if (j >= 2 * DM) {
      const int i = j - 2 * DM;
      float r = gsig[i];
      float z = gsig[i + DM];
      float n = tanhf(gxv + r * gh);       // gh here is hn (h-side pre-act)
      float hn = (1.0f - z) * n + z * hloc;
      hloc = hn;
      h16[i] = (_Float16)hn;
      outb[(size_t)t * DM + i] = hn;
    }
    __syncthreads();
    gxv = gxn;
  }
}

extern "C" void kernel_launch(void* const* d_in, const int* in_sizes, int n_in,
                              void* d_out, int out_size, void* d_ws, size_t ws_size,
                              hipStream_t stream) {
  const float* x   = (const float*)d_in[0];
  const float* W1  = (const float*)d_in[1];
  const float* b1  = (const float*)d_in[2];
  const float* Wih = (const float*)d_in[3];
  const float* bih = (const float*)d_in[4];
  const float* Whh = (const float*)d_in[5];
  const float* bhh = (const float*)d_in[6];
  float* out = (float*)d_out;

  char* ws = (char*)d_ws;
  __half* h  = (__half*)ws;                                   // [32768,512] fp16
  size_t h_bytes = (size_t)MTOT * DI * sizeof(__half);
  h_bytes = (h_bytes + 255) & ~(size_t)255;
  __half* gxbuf = (__half*)(ws + h_bytes);                    // [32768,768] fp16

  dim3 blk(256);
  // h = gelu(x @ W1^T + b1)
  gemm_bias<false, true><<<dim3(DI / 128, MTOT / 128), blk, 0, stream>>>(
      x, W1, b1, h, MTOT, DI, DM);
  // gx = h @ W_ih^T + b_ih
  gemm_bias<true, false><<<dim3(TG / 128, MTOT / 128), blk, 0, stream>>>(
      h, Wih, bih, gxbuf, MTOT, TG, DI);
  // GRU scan
  gru_scan<<<NB, 768, 0, stream>>>(gxbuf, Whh, bhh, out);
}

// Round 2
// 5860.729 us; speedup vs baseline: 20.5313x; 20.5313x over previous
//
#include <hip/hip_runtime.h>
#include <hip/hip_fp16.h>
#include <hip/hip_bf16.h>

#define DM   256      // d_model
#define DI   512      // d_inner
#define TG   768      // 3*d_model
#define TSEQ 4096
#define NB   8
#define MTOT (NB*TSEQ) // 32768

typedef _Float16 h2f __attribute__((ext_vector_type(2)));
typedef _Float16 h8f __attribute__((ext_vector_type(8)));

// ---------------- Phase 1: tiled fp32 GEMM, C = act(A @ W^T + bias) in fp16 ----
// A: [M,K] (fp32 or fp16), W: [N,K] fp32 row-major, C: [M,N] fp16
// 256 threads, 128x128 tile, BK=16, 8x8 micro-tile.
template<bool A_HALF, bool GELU_ACT>
__global__ __launch_bounds__(256) void gemm_bias(
    const void* __restrict__ Ap, const float* __restrict__ W,
    const float* __restrict__ bias, __half* __restrict__ C,
    int M, int N, int K)
{
  __shared__ float As[16][132];   // transposed: [k][m]
  __shared__ float Ws[16][132];   // transposed: [k][n]
  const int tid = threadIdx.x;
  const int tx = tid & 15, ty = tid >> 4;
  const int m0 = blockIdx.y * 128;
  const int n0 = blockIdx.x * 128;

  float acc[8][8] = {};

  for (int k0 = 0; k0 < K; k0 += 16) {
    // ---- stage A tile ----
    if constexpr (A_HALF) {
      const __half* A = (const __half*)Ap;
      int r = tid >> 1, seg = (tid & 1) * 8;          // 8 halves per thread
      float4 raw = *(const float4*)(A + (size_t)(m0 + r) * K + k0 + seg);
      const __half* hv = (const __half*)&raw;
      #pragma unroll
      for (int q = 0; q < 8; q++) As[seg + q][r] = __half2float(hv[q]);
    } else {
      const float* A = (const float*)Ap;
      #pragma unroll
      for (int rep = 0; rep < 2; rep++) {
        int r = (tid >> 2) + rep * 64;
        int seg = (tid & 3) * 4;
        float4 v = *(const float4*)(A + (size_t)(m0 + r) * K + k0 + seg);
        As[seg + 0][r] = v.x; As[seg + 1][r] = v.y;
        As[seg + 2][r] = v.z; As[seg + 3][r] = v.w;
      }
    }
    // ---- stage W tile ----
    #pragma unroll
    for (int rep = 0; rep < 2; rep++) {
      int r = (tid >> 2) + rep * 64;
      int seg = (tid & 3) * 4;
      float4 v = *(const float4*)(W + (size_t)(n0 + r) * K + k0 + seg);
      Ws[seg + 0][r] = v.x; Ws[seg + 1][r] = v.y;
      Ws[seg + 2][r] = v.z; Ws[seg + 3][r] = v.w;
    }
    __syncthreads();
    #pragma unroll
    for (int kk = 0; kk < 16; ++kk) {
      float a[8], b[8];
      *(float4*)&a[0] = *(const float4*)&As[kk][ty * 8];
      *(float4*)&a[4] = *(const float4*)&As[kk][ty * 8 + 4];
      *(float4*)&b[0] = *(const float4*)&Ws[kk][tx * 8];
      *(float4*)&b[4] = *(const float4*)&Ws[kk][tx * 8 + 4];
      #pragma unroll
      for (int i = 0; i < 8; i++)
        #pragma unroll
        for (int j = 0; j < 8; j++)
          acc[i][j] += a[i] * b[j];
    }
    __syncthreads();
  }

  #pragma unroll
  for (int i = 0; i < 8; i++) {
    int m = m0 + ty * 8 + i;
    #pragma unroll
    for (int j = 0; j < 8; j++) {
      int n = n0 + tx * 8 + j;
      float v = acc[i][j] + bias[n];
      if constexpr (GELU_ACT) {
        v = 0.5f * v * (1.0f + erff(v * 0.70710678118654752f));  // exact GELU
      }
      C[(size_t)m * N + n] = __float2half(v);
    }
  }
}

// ---------------- Phase 2: persistent GRU scan, one block per batch ----------
// 768 threads; thread j owns gate-row j of W_hh resident in VGPRs (128 x f16x2).
// CRITICAL: weight-load loop must be FULLY unrolled (compile-time indices) or
// w[] is allocated in scratch (rule #20) -> 100x slowdown (round-1 lesson:
// VGPR_Count was 84 with #pragma unroll 4).
// __launch_bounds__(768,3): 12 waves = 3 waves/SIMD -> VGPR cap ~170, fits w.
__global__ __launch_bounds__(768, 3) void gru_scan(
    const __half* __restrict__ gx,   // [B, T, 768] fp16 (includes b_ih)
    const float*  __restrict__ Whh,  // [768, 256]
    const float*  __restrict__ bhh,  // [768]
    float* __restrict__ out)         // [B, T, 256]
{
  const int b = blockIdx.x;
  const int j = threadIdx.x;   // 0..767

  __shared__ __align__(16) _Float16 h16[DM];  // f16 copy of state for dot input
  __shared__ float gsig[2 * DM];              // r, z sigmoids

  // Load W_hh row j -> 128 packed f16x2 registers (fully unrolled!)
  h2f w[128];
  const float* wrow = Whh + (size_t)j * DM;
  #pragma unroll
  for (int k4 = 0; k4 < 64; k4++) {
    float4 f = ((const float4*)wrow)[k4];
    h2f t0; t0[0] = (_Float16)f.x; t0[1] = (_Float16)f.y;
    h2f t1; t1[0] = (_Float16)f.z; t1[1] = (_Float16)f.w;
    w[2 * k4]     = t0;
    w[2 * k4 + 1] = t1;
  }
  const float bias = bhh[j];
  float hloc = 0.0f;           // fp32 state (only meaningful for n-threads)

  if (j < DM) h16[j] = (_Float16)0.0f;
  __syncthreads();

  const __half* gxb = gx + (size_t)b * TSEQ * TG;
  float* outb = out + (size_t)b * TSEQ * DM;

  float gxv = __half2float(gxb[j]);

  for (int t = 0; t < TSEQ; ++t) {
    // ---- gh_j = b_hh[j] + dot(W_hh[j,:], h_prev) via v_dot2_f32_f16 ----
    // h broadcast from LDS via ds_read_b128 (same-address -> conflict-free).
    float a0 = bias, a1 = 0.f, a2 = 0.f, a3 = 0.f;
    const h8f* hp8 = (const h8f*)h16;
    #pragma unroll
    for (int k = 0; k < 32; k++) {
      union { h8f v; h2f p[4]; } u;
      u.v = hp8[k];
      a0 = __builtin_amdgcn_fdot2(w[4 * k + 0], u.p[0], a0, false);
      a1 = __builtin_amdgcn_fdot2(w[4 * k + 1], u.p[1], a1, false);
      a2 = __builtin_amdgcn_fdot2(w[4 * k + 2], u.p[2], a2, false);
      a3 = __builtin_amdgcn_fdot2(w[4 * k + 3], u.p[3], a3, false);
    }
    float gh = (a0 + a1) + (a2 + a3);

    // prefetch next timestep's gx
    float gxn = 0.f;
    if (t + 1 < TSEQ) gxn = __half2float(gxb[(size_t)(t + 1) * TG + j]);

    if (j < 2 * DM) {
      // r (j<256) and z (256<=j<512) gates
      float s = 1.0f / (1.0f + __expf(-(gxv + gh)));
      gsig[j] = s;
    }
    __syncthreads();
    if (j >= 2 * DM) {
      const int i = j - 2 * DM;
      float r = gsig[i];
      float z = gsig[i + DM];
      float n = tanhf(gxv + r * gh);       // gh here is hn (h-side pre-act)
      float hn = (1.0f - z) * n + z * hloc;
      hloc = hn;
      h16[i] = (_Float16)hn;
      outb[(size_t)t * DM + i] = hn;
    }
    __syncthreads();
    gxv = gxn;
  }
}

extern "C" void kernel_launch(void* const* d_in, const int* in_sizes, int n_in,
                              void* d_out, int out_size, void* d_ws, size_t ws_size,
                              hipStream_t stream) {
  const float* x   = (const float*)d_in[0];
  const float* W1  = (const float*)d_in[1];
  const float* b1  = (const float*)d_in[2];
  const float* Wih = (const float*)d_in[3];
  const float* bih = (const float*)d_in[4];
  const float* Whh = (const float*)d_in[5];
  const float* bhh = (const float*)d_in[6];
  float* out = (float*)d_out;

  char* ws = (char*)d_ws;
  __half* h  = (__half*)ws;                                   // [32768,512] fp16
  size_t h_bytes = (size_t)MTOT * DI * sizeof(__half);
  h_bytes = (h_bytes + 255) & ~(size_t)255;
  __half* gxbuf = (__half*)(ws + h_bytes);                    // [32768,768] fp16

  dim3 blk(256);
  // h = gelu(x @ W1^T + b1)
  gemm_bias<false, true><<<dim3(DI / 128, MTOT / 128), blk, 0, stream>>>(
      x, W1, b1, h, MTOT, DI, DM);
  // gx = h @ W_ih^T + b_ih
  gemm_bias<true, false><<<dim3(TG / 128, MTOT / 128), blk, 0, stream>>>(
      h, Wih, bih, gxbuf, MTOT, TG, DI);
  // GRU scan
  gru_scan<<<NB, 768, 0, stream>>>(gxbuf, Whh, bhh, out);
}

// Round 3
// 5600.299 us; speedup vs baseline: 21.4861x; 1.0465x over previous
//
#include <hip/hip_runtime.h>
#include <hip/hip_fp16.h>
#include <hip/hip_bf16.h>

#define DM   256      // d_model
#define DI   512      // d_inner
#define TG   768      // 3*d_model
#define TSEQ 4096
#define NB   8
#define MTOT (NB*TSEQ) // 32768

typedef _Float16 h2f __attribute__((ext_vector_type(2)));
typedef _Float16 h8f __attribute__((ext_vector_type(8)));

// ---------------- Phase 1: tiled fp32 GEMM, C = act(A @ W^T + bias) in fp16 ----
template<bool A_HALF, bool GELU_ACT>
__global__ __launch_bounds__(256) void gemm_bias(
    const void* __restrict__ Ap, const float* __restrict__ W,
    const float* __restrict__ bias, __half* __restrict__ C,
    int M, int N, int K)
{
  __shared__ float As[16][132];   // transposed: [k][m]
  __shared__ float Ws[16][132];   // transposed: [k][n]
  const int tid = threadIdx.x;
  const int tx = tid & 15, ty = tid >> 4;
  const int m0 = blockIdx.y * 128;
  const int n0 = blockIdx.x * 128;

  float acc[8][8] = {};

  for (int k0 = 0; k0 < K; k0 += 16) {
    if constexpr (A_HALF) {
      const __half* A = (const __half*)Ap;
      int r = tid >> 1, seg = (tid & 1) * 8;
      float4 raw = *(const float4*)(A + (size_t)(m0 + r) * K + k0 + seg);
      const __half* hv = (const __half*)&raw;
      #pragma unroll
      for (int q = 0; q < 8; q++) As[seg + q][r] = __half2float(hv[q]);
    } else {
      const float* A = (const float*)Ap;
      #pragma unroll
      for (int rep = 0; rep < 2; rep++) {
        int r = (tid >> 2) + rep * 64;
        int seg = (tid & 3) * 4;
        float4 v = *(const float4*)(A + (size_t)(m0 + r) * K + k0 + seg);
        As[seg + 0][r] = v.x; As[seg + 1][r] = v.y;
        As[seg + 2][r] = v.z; As[seg + 3][r] = v.w;
      }
    }
    #pragma unroll
    for (int rep = 0; rep < 2; rep++) {
      int r = (tid >> 2) + rep * 64;
      int seg = (tid & 3) * 4;
      float4 v = *(const float4*)(W + (size_t)(n0 + r) * K + k0 + seg);
      Ws[seg + 0][r] = v.x; Ws[seg + 1][r] = v.y;
      Ws[seg + 2][r] = v.z; Ws[seg + 3][r] = v.w;
    }
    __syncthreads();
    #pragma unroll
    for (int kk = 0; kk < 16; ++kk) {
      float a[8], b[8];
      *(float4*)&a[0] = *(const float4*)&As[kk][ty * 8];
      *(float4*)&a[4] = *(const float4*)&As[kk][ty * 8 + 4];
      *(float4*)&b[0] = *(const float4*)&Ws[kk][tx * 8];
      *(float4*)&b[4] = *(const float4*)&Ws[kk][tx * 8 + 4];
      #pragma unroll
      for (int i = 0; i < 8; i++)
        #pragma unroll
        for (int j = 0; j < 8; j++)
          acc[i][j] += a[i] * b[j];
    }
    __syncthreads();
  }

  #pragma unroll
  for (int i = 0; i < 8; i++) {
    int m = m0 + ty * 8 + i;
    #pragma unroll
    for (int j = 0; j < 8; j++) {
      int n = n0 + tx * 8 + j;
      float v = acc[i][j] + bias[n];
      if constexpr (GELU_ACT) {
        v = 0.5f * v * (1.0f + erff(v * 0.70710678118654752f));  // exact GELU
      }
      C[(size_t)m * N + n] = __float2half(v);
    }
  }
}

// ---------------- DPP quad butterfly helpers (VALU, no LDS pipe) -------------
__device__ __forceinline__ float dpp_xor1_add(float v) {
  int i = __builtin_bit_cast(int, v);
  int s = __builtin_amdgcn_update_dpp(i, i, 0xB1, 0xF, 0xF, true); // quad_perm [1,0,3,2]
  return v + __builtin_bit_cast(float, s);
}
__device__ __forceinline__ float dpp_xor2_add(float v) {
  int i = __builtin_bit_cast(int, v);
  int s = __builtin_amdgcn_update_dpp(i, i, 0x4E, 0xF, 0xF, true); // quad_perm [2,3,0,1]
  return v + __builtin_bit_cast(float, s);
}

// ---------------- Phase 2: persistent GRU scan, one block per batch ----------
// K-split x4: lane-quad (4 lanes) covers rows 4g..4g+3; lane q owns interleaved
// 16B chunks {q, q+4, ..., q+28} of h (conflict-free banks, 8 ds_read_b128 per
// thread per step instead of 32). Weights stored per-thread in the SAME chunk
// order so all w[] indices are compile-time (rule #20). Quad reduce via DPP.
// sched_barrier(0) fences cap live ds_reads/global loads so the 128 w regs
// survive register allocation (round-2 lesson: VGPR=84 means w spilled).
__global__ __launch_bounds__(768, 3) void gru_scan(
    const __half* __restrict__ gx,   // [B, T, 768] fp16 (includes b_ih)
    const float*  __restrict__ Whh,  // [768, 256]
    const float*  __restrict__ bhh,  // [768]
    float* __restrict__ out)         // [B, T, 256]
{
  const int b  = blockIdx.x;
  const int j  = threadIdx.x;   // 0..767 ; owns gate-row j
  const int g  = j >> 2;        // quad id
  const int q  = j & 3;         // k-quarter within quad
  const int row0 = g << 2;

  __shared__ __align__(16) _Float16 h16[DM];
  __shared__ float gsig[2 * DM];

  // wrot[r*32 + 4i+m] = Whh[row0+r][8*(q+4i) + 2m .. +1] as f16x2
  h2f w[128];
  #pragma unroll
  for (int r = 0; r < 4; ++r) {
    const float* wrow = Whh + (size_t)(row0 + r) * DM;
    #pragma unroll
    for (int i = 0; i < 8; ++i) {
      const float* p = wrow + 8 * (q + 4 * i);
      float4 f0 = *(const float4*)(p);
      float4 f1 = *(const float4*)(p + 4);
      h2f t0; t0[0] = (_Float16)f0.x; t0[1] = (_Float16)f0.y;
      h2f t1; t1[0] = (_Float16)f0.z; t1[1] = (_Float16)f0.w;
      h2f t2; t2[0] = (_Float16)f1.x; t2[1] = (_Float16)f1.y;
      h2f t3; t3[0] = (_Float16)f1.z; t3[1] = (_Float16)f1.w;
      w[r * 32 + 4 * i + 0] = t0;
      w[r * 32 + 4 * i + 1] = t1;
      w[r * 32 + 4 * i + 2] = t2;
      w[r * 32 + 4 * i + 3] = t3;
      __builtin_amdgcn_sched_barrier(0);   // <=2 loads in flight: protect w regs
    }
  }
  const float bias = bhh[j];
  float hloc = 0.0f;

  if (j < DM) h16[j] = (_Float16)0.0f;
  __syncthreads();

  const __half* gxb = gx + (size_t)b * TSEQ * TG + j;
  float* outb = out + (size_t)b * TSEQ * DM;

  float gxv = __half2float(gxb[0]);
  const h8f* hp8 = (const h8f*)h16;

  for (int t = 0; t < TSEQ; ++t) {
    // ---- 4 partial dots (rows row0..row0+3, this lane's K-chunks) ----
    float a0 = 0.f, a1 = 0.f, a2 = 0.f, a3 = 0.f;
    #pragma unroll
    for (int i = 0; i < 8; ++i) {
      union { h8f v; h2f p[4]; } u;
      u.v = hp8[q + 4 * i];
      a0 = __builtin_amdgcn_fdot2(w[      4 * i + 0], u.p[0], a0, false);
      a0 = __builtin_amdgcn_fdot2(w[      4 * i + 1], u.p[1], a0, false);
      a0 = __builtin_amdgcn_fdot2(w[      4 * i + 2], u.p[2], a0, false);
      a0 = __builtin_amdgcn_fdot2(w[      4 * i + 3], u.p[3], a0, false);
      a1 = __builtin_amdgcn_fdot2(w[ 32 + 4 * i + 0], u.p[0], a1, false);
      a1 = __builtin_amdgcn_fdot2(w[ 32 + 4 * i + 1], u.p[1], a1, false);
      a1 = __builtin_amdgcn_fdot2(w[ 32 + 4 * i + 2], u.p[2], a1, false);
      a1 = __builtin_amdgcn_fdot2(w[ 32 + 4 * i + 3], u.p[3], a1, false);
      a2 = __builtin_amdgcn_fdot2(w[ 64 + 4 * i + 0], u.p[0], a2, false);
      a2 = __builtin_amdgcn_fdot2(w[ 64 + 4 * i + 1], u.p[1], a2, false);
      a2 = __builtin_amdgcn_fdot2(w[ 64 + 4 * i + 2], u.p[2], a2, false);
      a2 = __builtin_amdgcn_fdot2(w[ 64 + 4 * i + 3], u.p[3], a2, false);
      a3 = __builtin_amdgcn_fdot2(w[ 96 + 4 * i + 0], u.p[0], a3, false);
      a3 = __builtin_amdgcn_fdot2(w[ 96 + 4 * i + 1], u.p[1], a3, false);
      a3 = __builtin_amdgcn_fdot2(w[ 96 + 4 * i + 2], u.p[2], a3, false);
      a3 = __builtin_amdgcn_fdot2(w[ 96 + 4 * i + 3], u.p[3], a3, false);
      if (i & 1) __builtin_amdgcn_sched_barrier(0);  // <=2 h8f live
    }
    // ---- quad butterfly: all 4 lanes get all 4 full row sums ----
    a0 = dpp_xor2_add(dpp_xor1_add(a0));
    a1 = dpp_xor2_add(dpp_xor1_add(a1));
    a2 = dpp_xor2_add(dpp_xor1_add(a2));
    a3 = dpp_xor2_add(dpp_xor1_add(a3));
    float lo = (q & 1) ? a1 : a0;
    float hi = (q & 1) ? a3 : a2;
    float gh = ((q & 2) ? hi : lo) + bias;   // this lane's row-j pre-activation

    // prefetch next timestep's gx
    float gxn = 0.f;
    if (t + 1 < TSEQ) gxn = __half2float(gxb[(size_t)(t + 1) * TG]);

    if (j < 2 * DM) {
      // r (j<256) and z (256<=j<512) gates
      gsig[j] = 1.0f / (1.0f + __expf(-(gxv + gh)));
    }
    __syncthreads();
    if (j >= 2 * DM) {
      const int i2 = j - 2 * DM;
      float r = gsig[i2];
      float z = gsig[i2 + DM];
      float n = tanhf(gxv + r * gh);         // gh = hn (h-side pre-act)
      float hn = (1.0f - z) * n + z * hloc;
      hloc = hn;
      h16[i2] = (_Float16)hn;
      outb[(size_t)t * DM + i2] = hn;
    }
    __syncthreads();
    gxv = gxn;
  }
}

extern "C" void kernel_launch(void* const* d_in, const int* in_sizes, int n_in,
                              void* d_out, int out_size, void* d_ws, size_t ws_size,
                              hipStream_t stream) {
  const float* x   = (const float*)d_in[0];
  const float* W1  = (const float*)d_in[1];
  const float* b1  = (const float*)d_in[2];
  const float* Wih = (const float*)d_in[3];
  const float* bih = (const float*)d_in[4];
  const float* Whh = (const float*)d_in[5];
  const float* bhh = (const float*)d_in[6];
  float* out = (float*)d_out;

  char* ws = (char*)d_ws;
  __half* h  = (__half*)ws;                                   // [32768,512] fp16
  size_t h_bytes = (size_t)MTOT * DI * sizeof(__half);
  h_bytes = (h_bytes + 255) & ~(size_t)255;
  __half* gxbuf = (__half*)(ws + h_bytes);                    // [32768,768] fp16

  dim3 blk(256);
  gemm_bias<false, true><<<dim3(DI / 128, MTOT / 128), blk, 0, stream>>>(
      x, W1, b1, h, MTOT, DI, DM);
  gemm_bias<true, false><<<dim3(TG / 128, MTOT / 128), blk, 0, stream>>>(
      h, Wih, bih, gxbuf, MTOT, TG, DI);
  gru_scan<<<NB, 768, 0, stream>>>(gxbuf, Whh, bhh, out);
}